// Round 9
// baseline (255.698 us; speedup 1.0000x reference)
//
#include <hip/hip_runtime.h>

// WeightedTensorProduct: N=16384 nodes, F=128, ranks 0..3 (sizes 1,3,9,27).
// x,y: [N, 5120] f32 (row: [128] | [128][3] | [128][9] | [128][27]).
// weights: [23][128] f32. out: [N, 5120] f32.
//
// Wave-autonomous design: one 64-lane wave per block, quarter-node
// (32 features), 10 KB LDS. NO barriers anywhere — a single wave only needs
// s_waitcnt vmcnt(0) after its global->LDS DMA and lgkmcnt(0) between its
// LDS stage-writes and readback (lanes are lockstep). 16 blocks/CU, each an
// independent DMA->compute->store stream -> covers HBM latency by pure TLP
// without the phase-lockstep that capped rounds 6-8 at ~3.7 TB/s.

#define FF 128
#define ROW 5120
#define QROW 1280   // packed quarter-row floats (32 features x 40)

typedef float floatx4 __attribute__((ext_vector_type(4)));

__device__ __constant__ float NORMS[23] = {
    1.0f, 1.0f, 2.0f/3.0f, 0.4f,                          // (0,0,0)(1,1,0)(2,2,0)(3,3,0)
    1.0f, 1.0f, 1.0f, 1.0f, 2.0f/3.0f, 2.0f/3.0f,         // l3=1 paths
    1.0f, 0.75f, 1.0f, 1.0f, 1.0f, 1.0f, 0.75f,           // l3=2 paths
    1.0f, 5.0f/9.0f, 5.0f/9.0f, 5.0f/6.0f, 1.0f, 5.0f/6.0f // l3=3 paths
};

#define GL2LDS(g, l)  __builtin_amdgcn_global_load_lds(                      \
        (const __attribute__((address_space(1))) void*)(g),                  \
        (__attribute__((address_space(3))) void*)(l), 16, 0, 0)

__global__ __launch_bounds__(64, 4) void wtp_kernel(
    const float* __restrict__ x, const float* __restrict__ y,
    const float* __restrict__ w, float* __restrict__ out)
{
    __shared__ float buf[2 * QROW];   // 10 KB: packed x-quarter | y-quarter

    const int lane  = threadIdx.x;
    const int f     = lane & 31;              // local feature
    const int h     = lane >> 5;              // 0 -> l3=0,1,2 ; 1 -> l3=3
    const int n     = blockIdx.x >> 2;
    const int fbase = (blockIdx.x & 3) << 5;  // 0,32,64,96

    const float* xr = x + (size_t)n * ROW;
    const float* yr = y + (size_t)n * ROW;
    float* orow     = out + (size_t)n * ROW;

    // per-lane global offsets for the 5 DMA/store issues (packed layout:
    // r0 [0,32) r1 [32,128) r2 [128,416) r3 [416,1280); all boundaries %4==0)
    int goff[5];
    #pragma unroll
    for (int i = 0; i < 5; ++i) {
        const int o = i * 256 + lane * 4;
        int r;
        if      (o < 32)  r = fbase         + o;
        else if (o < 128) r = 128  + fbase*3  + (o - 32);
        else if (o < 416) r = 512  + fbase*9  + (o - 128);
        else              r = 1664 + fbase*27 + (o - 416);
        goff[i] = r;
    }

    // ---- coalesced DMA of both quarter-rows into LDS (16B/lane) ----
    #pragma unroll
    for (int i = 0; i < 5; ++i) {
        GL2LDS(xr + goff[i], buf + i * 256);
        GL2LDS(yr + goff[i], buf + QROW + i * 256);
    }

    // weights overlap the DMA in-flight window
    float c[23];
    #pragma unroll
    for (int p = 0; p < 23; ++p) c[p] = NORMS[p] * w[p * FF + fbase + f];

    asm volatile("s_waitcnt vmcnt(0)" ::: "memory");   // single wave: no barrier

    // ---- rank 0..2 -> registers; rank-3 read from LDS at use ----
    const float* bx = buf;
    const float* by = buf + QROW;
    const float x0 = bx[f], y0 = by[f];
    float x1[3], y1[3], x2[9], y2[9];
    #pragma unroll
    for (int j = 0; j < 3; ++j)  x1[j] = bx[32  + f*3 + j];
    #pragma unroll
    for (int j = 0; j < 3; ++j)  y1[j] = by[32  + f*3 + j];
    #pragma unroll
    for (int j = 0; j < 9; ++j)  x2[j] = bx[128 + f*9 + j];
    #pragma unroll
    for (int j = 0; j < 9; ++j)  y2[j] = by[128 + f*9 + j];

    const float* bx3 = bx + 416 + f*27;   // stride 27 (odd) -> conflict-free
    const float* by3 = by + 416 + f*27;

    float o0, o1[3], o2[9], o3[27];

    if (h == 0) {
        // ---- l3 = 0 ----
        {
            float acc = c[0] * (x0 * y0);
            float d3 = 0.f;
            #pragma unroll
            for (int u = 0; u < 3; ++u) d3 += x1[u] * y1[u];
            acc += c[1] * d3;
            float d9 = 0.f;
            #pragma unroll
            for (int t = 0; t < 9; ++t) d9 += x2[t] * y2[t];
            acc += c[2] * d9;
            float d27 = 0.f;
            #pragma unroll
            for (int t = 0; t < 27; ++t) d27 += bx3[t] * by3[t];
            acc += c[3] * d27;
            o0 = acc;
        }
        // ---- l3 = 1 ----
        #pragma unroll
        for (int d = 0; d < 3; ++d) {
            float acc = c[4] * (x0 * y1[d]) + c[5] * (x1[d] * y0);
            float s6 = 0.f, s7 = 0.f, s8 = 0.f, s9 = 0.f;
            #pragma unroll
            for (int u = 0; u < 3; ++u) s6 += x1[u] * y2[u*3 + d];     // (1,2,1)
            #pragma unroll
            for (int u = 0; u < 3; ++u) s7 += x2[d*3 + u] * y1[u];     // (2,1,1)
            #pragma unroll
            for (int t = 0; t < 9; ++t) s8 += x2[t] * by3[t*3 + d];    // (2,3,1)
            #pragma unroll
            for (int t = 0; t < 9; ++t) s9 += bx3[d*9 + t] * y2[t];    // (3,2,1)
            o1[d] = acc + c[6]*s6 + c[7]*s7 + c[8]*s8 + c[9]*s9;
        }
        // ---- l3 = 2 ----  (t = a*3 + d)
        #pragma unroll
        for (int t = 0; t < 9; ++t) {
            const int a = t / 3, d = t % 3;
            float acc = c[10] * (x0 * y2[t]) + c[11] * (x1[a] * y1[d])
                      + c[13] * (x2[t] * y0);
            float s12 = 0.f, s14 = 0.f, s15 = 0.f, s16 = 0.f;
            #pragma unroll
            for (int u = 0; u < 3; ++u) s12 += x1[u] * by3[u*9 + t];       // (1,3,2)
            #pragma unroll
            for (int u = 0; u < 3; ++u) s14 += x2[a*3 + u] * y2[u*3 + d];  // (2,2,2)
            #pragma unroll
            for (int u = 0; u < 3; ++u) s15 += bx3[t*3 + u] * y1[u];       // (3,1,2)
            #pragma unroll
            for (int s = 0; s < 9; ++s) s16 += bx3[a*9 + s] * by3[s*3 + d];// (3,3,2)
            o2[t] = acc + c[12]*s12 + c[14]*s14 + c[15]*s15 + c[16]*s16;
        }
    } else {
        // ---- l3 = 3 ----  (q = a*9 + t9, also q = r*3 + e)
        #pragma unroll
        for (int q = 0; q < 27; ++q) {
            const int a = q / 9, t9 = q % 9, r = q / 3, e = q % 3;
            float acc = c[17] * (x0 * by3[q]) + c[18] * (x1[a] * y2[t9])
                      + c[19] * (x2[r] * y1[e]) + c[21] * (bx3[q] * y0);
            float s20 = 0.f, s22 = 0.f;
            #pragma unroll
            for (int u = 0; u < 3; ++u) s20 += x2[a*3 + u] * by3[u*9 + t9]; // (2,3,3)
            #pragma unroll
            for (int u = 0; u < 3; ++u) s22 += bx3[r*3 + u] * y2[u*3 + e];  // (3,2,3)
            o3[q] = acc + c[20]*s20 + c[22]*s22;
        }
    }

    // ---- stage outputs into the (dead) x-region of LDS ----
    // h=0 writes [0,416); h=1 writes [416,1280). All compute LDS reads are
    // before the branch join (lockstep exec-masked halves), so no race.
    if (h == 0) {
        buf[f] = o0;
        #pragma unroll
        for (int d = 0; d < 3; ++d) buf[32  + f*3 + d] = o1[d];
        #pragma unroll
        for (int t = 0; t < 9; ++t) buf[128 + f*9 + t] = o2[t];
    } else {
        #pragma unroll
        for (int q = 0; q < 27; ++q) buf[416 + f*27 + q] = o3[q];
    }
    asm volatile("s_waitcnt lgkmcnt(0)" ::: "memory");  // stage-writes retired
    __builtin_amdgcn_sched_barrier(0);                  // keep reads below

    // ---- coalesced NT float4 store (same offsets as the DMA) ----
    #pragma unroll
    for (int i = 0; i < 5; ++i) {
        floatx4 v = *(const floatx4*)(buf + i * 256 + lane * 4);
        __builtin_nontemporal_store(v, (floatx4*)(orow + goff[i]));
    }
}

extern "C" void kernel_launch(void* const* d_in, const int* in_sizes, int n_in,
                              void* d_out, int out_size, void* d_ws, size_t ws_size,
                              hipStream_t stream) {
    const float* x = (const float*)d_in[0];
    const float* y = (const float*)d_in[1];
    const float* w = (const float*)d_in[2];
    float* out = (float*)d_out;

    const int n_nodes = in_sizes[0] / ROW;       // 16384
    dim3 grid(n_nodes * 4), block(64);           // quarter-node per 1-wave block
    hipLaunchKernelGGL(wtp_kernel, grid, block, 0, stream, x, y, w, out);
}

// Round 10
// 201.598 us; speedup vs baseline: 1.2684x; 1.2684x over previous
//
#include <hip/hip_runtime.h>

// WeightedTensorProduct: N=16384 nodes, F=128, ranks 0..3 (sizes 1,3,9,27).
// x,y: [N, 5120] f32 (row: [128] | [128][3] | [128][9] | [128][27]).
// weights: [23][128] f32. out: [N, 5120] f32.
//
// Wave-autonomous design: one 64-lane wave per block, quarter-node
// (32 features), 10 KB LDS, NO barriers (single wave: vmcnt/lgkmcnt only).
// 16 blocks/CU = 16 independent DMA->compute->store streams per CU.
// Round-9 lesson: __launch_bounds__(64,4) capped VGPR at 64 -> ~300 MB of
// scratch spill traffic. (64,2) gives the register allocator room (~128);
// LDS still limits occupancy to 16 waves/CU, so nothing is lost.

#define FF 128
#define ROW 5120
#define QROW 1280   // packed quarter-row floats (32 features x 40)

typedef float floatx4 __attribute__((ext_vector_type(4)));

__device__ __constant__ float NORMS[23] = {
    1.0f, 1.0f, 2.0f/3.0f, 0.4f,                          // (0,0,0)(1,1,0)(2,2,0)(3,3,0)
    1.0f, 1.0f, 1.0f, 1.0f, 2.0f/3.0f, 2.0f/3.0f,         // l3=1 paths
    1.0f, 0.75f, 1.0f, 1.0f, 1.0f, 1.0f, 0.75f,           // l3=2 paths
    1.0f, 5.0f/9.0f, 5.0f/9.0f, 5.0f/6.0f, 1.0f, 5.0f/6.0f // l3=3 paths
};

#define GL2LDS(g, l)  __builtin_amdgcn_global_load_lds(                      \
        (const __attribute__((address_space(1))) void*)(g),                  \
        (__attribute__((address_space(3))) void*)(l), 16, 0, 0)

__global__ __launch_bounds__(64, 2) void wtp_kernel(
    const float* __restrict__ x, const float* __restrict__ y,
    const float* __restrict__ w, float* __restrict__ out)
{
    __shared__ float buf[2 * QROW];   // 10 KB: packed x-quarter | y-quarter

    const int lane  = threadIdx.x;
    const int f     = lane & 31;              // local feature
    const int h     = lane >> 5;              // 0 -> l3=0,1,2 ; 1 -> l3=3
    const int n     = blockIdx.x >> 2;
    const int fbase = (blockIdx.x & 3) << 5;  // 0,32,64,96

    const float* xr = x + (size_t)n * ROW;
    const float* yr = y + (size_t)n * ROW;
    float* orow     = out + (size_t)n * ROW;

    // per-lane global offsets for the 5 DMA/store issues (packed layout:
    // r0 [0,32) r1 [32,128) r2 [128,416) r3 [416,1280); all boundaries %4==0)
    int goff[5];
    #pragma unroll
    for (int i = 0; i < 5; ++i) {
        const int o = i * 256 + lane * 4;
        int r;
        if      (o < 32)  r = fbase         + o;
        else if (o < 128) r = 128  + fbase*3  + (o - 32);
        else if (o < 416) r = 512  + fbase*9  + (o - 128);
        else              r = 1664 + fbase*27 + (o - 416);
        goff[i] = r;
    }

    // ---- coalesced DMA of both quarter-rows into LDS (16B/lane) ----
    #pragma unroll
    for (int i = 0; i < 5; ++i) {
        GL2LDS(xr + goff[i], buf + i * 256);
        GL2LDS(yr + goff[i], buf + QROW + i * 256);
    }

    // weights overlap the DMA in-flight window
    float c[23];
    #pragma unroll
    for (int p = 0; p < 23; ++p) c[p] = NORMS[p] * w[p * FF + fbase + f];

    asm volatile("s_waitcnt vmcnt(0)" ::: "memory");   // single wave: no barrier

    // ---- rank 0..2 -> registers; rank-3 read from LDS at use ----
    const float* bx = buf;
    const float* by = buf + QROW;
    const float x0 = bx[f], y0 = by[f];
    float x1[3], y1[3], x2[9], y2[9];
    #pragma unroll
    for (int j = 0; j < 3; ++j)  x1[j] = bx[32  + f*3 + j];
    #pragma unroll
    for (int j = 0; j < 3; ++j)  y1[j] = by[32  + f*3 + j];
    #pragma unroll
    for (int j = 0; j < 9; ++j)  x2[j] = bx[128 + f*9 + j];
    #pragma unroll
    for (int j = 0; j < 9; ++j)  y2[j] = by[128 + f*9 + j];

    const float* bx3 = bx + 416 + f*27;   // stride 27 (odd) -> conflict-free
    const float* by3 = by + 416 + f*27;

    float o0, o1[3], o2[9], o3[27];

    if (h == 0) {
        // ---- l3 = 0 ----
        {
            float acc = c[0] * (x0 * y0);
            float d3 = 0.f;
            #pragma unroll
            for (int u = 0; u < 3; ++u) d3 += x1[u] * y1[u];
            acc += c[1] * d3;
            float d9 = 0.f;
            #pragma unroll
            for (int t = 0; t < 9; ++t) d9 += x2[t] * y2[t];
            acc += c[2] * d9;
            float d27 = 0.f;
            #pragma unroll
            for (int t = 0; t < 27; ++t) d27 += bx3[t] * by3[t];
            acc += c[3] * d27;
            o0 = acc;
        }
        // ---- l3 = 1 ----
        #pragma unroll
        for (int d = 0; d < 3; ++d) {
            float acc = c[4] * (x0 * y1[d]) + c[5] * (x1[d] * y0);
            float s6 = 0.f, s7 = 0.f, s8 = 0.f, s9 = 0.f;
            #pragma unroll
            for (int u = 0; u < 3; ++u) s6 += x1[u] * y2[u*3 + d];     // (1,2,1)
            #pragma unroll
            for (int u = 0; u < 3; ++u) s7 += x2[d*3 + u] * y1[u];     // (2,1,1)
            #pragma unroll
            for (int t = 0; t < 9; ++t) s8 += x2[t] * by3[t*3 + d];    // (2,3,1)
            #pragma unroll
            for (int t = 0; t < 9; ++t) s9 += bx3[d*9 + t] * y2[t];    // (3,2,1)
            o1[d] = acc + c[6]*s6 + c[7]*s7 + c[8]*s8 + c[9]*s9;
        }
        // ---- l3 = 2 ----  (t = a*3 + d)
        #pragma unroll
        for (int t = 0; t < 9; ++t) {
            const int a = t / 3, d = t % 3;
            float acc = c[10] * (x0 * y2[t]) + c[11] * (x1[a] * y1[d])
                      + c[13] * (x2[t] * y0);
            float s12 = 0.f, s14 = 0.f, s15 = 0.f, s16 = 0.f;
            #pragma unroll
            for (int u = 0; u < 3; ++u) s12 += x1[u] * by3[u*9 + t];       // (1,3,2)
            #pragma unroll
            for (int u = 0; u < 3; ++u) s14 += x2[a*3 + u] * y2[u*3 + d];  // (2,2,2)
            #pragma unroll
            for (int u = 0; u < 3; ++u) s15 += bx3[t*3 + u] * y1[u];       // (3,1,2)
            #pragma unroll
            for (int s = 0; s < 9; ++s) s16 += bx3[a*9 + s] * by3[s*3 + d];// (3,3,2)
            o2[t] = acc + c[12]*s12 + c[14]*s14 + c[15]*s15 + c[16]*s16;
        }
    } else {
        // ---- l3 = 3 ----  (q = a*9 + t9, also q = r*3 + e)
        #pragma unroll
        for (int q = 0; q < 27; ++q) {
            const int a = q / 9, t9 = q % 9, r = q / 3, e = q % 3;
            float acc = c[17] * (x0 * by3[q]) + c[18] * (x1[a] * y2[t9])
                      + c[19] * (x2[r] * y1[e]) + c[21] * (bx3[q] * y0);
            float s20 = 0.f, s22 = 0.f;
            #pragma unroll
            for (int u = 0; u < 3; ++u) s20 += x2[a*3 + u] * by3[u*9 + t9]; // (2,3,3)
            #pragma unroll
            for (int u = 0; u < 3; ++u) s22 += bx3[r*3 + u] * y2[u*3 + e];  // (3,2,3)
            o3[q] = acc + c[20]*s20 + c[22]*s22;
        }
    }

    // ---- stage outputs into the (dead) x-region of LDS ----
    // h=0 writes [0,416); h=1 writes [416,1280). All compute LDS reads are
    // before the branch join (lockstep exec-masked halves), so no race.
    if (h == 0) {
        buf[f] = o0;
        #pragma unroll
        for (int d = 0; d < 3; ++d) buf[32  + f*3 + d] = o1[d];
        #pragma unroll
        for (int t = 0; t < 9; ++t) buf[128 + f*9 + t] = o2[t];
    } else {
        #pragma unroll
        for (int q = 0; q < 27; ++q) buf[416 + f*27 + q] = o3[q];
    }
    asm volatile("s_waitcnt lgkmcnt(0)" ::: "memory");  // stage-writes retired
    __builtin_amdgcn_sched_barrier(0);                  // keep reads below

    // ---- coalesced NT float4 store (same offsets as the DMA) ----
    #pragma unroll
    for (int i = 0; i < 5; ++i) {
        floatx4 v = *(const floatx4*)(buf + i * 256 + lane * 4);
        __builtin_nontemporal_store(v, (floatx4*)(orow + goff[i]));
    }
}

extern "C" void kernel_launch(void* const* d_in, const int* in_sizes, int n_in,
                              void* d_out, int out_size, void* d_ws, size_t ws_size,
                              hipStream_t stream) {
    const float* x = (const float*)d_in[0];
    const float* y = (const float*)d_in[1];
    const float* w = (const float*)d_in[2];
    float* out = (float*)d_out;

    const int n_nodes = in_sizes[0] / ROW;       // 16384
    dim3 grid(n_nodes * 4), block(64);           // quarter-node per 1-wave block
    hipLaunchKernelGGL(wtp_kernel, grid, block, 0, stream, x, y, w, out);
}